// Round 4
// baseline (186.440 us; speedup 1.0000x reference)
//
#include <hip/hip_runtime.h>
#include <stdint.h>

#define IN_F 512
#define OUT_F 512
#define NROWS 8192
#define NSLOT 12                 // 11 spline slots + 1 base(x) slot per in-feature
#define KTOT (IN_F * NSLOT)      // 6144
#define K16S (KTOT / 16)         // 384 k16-steps
#define KSPLIT 4                 // grid = 64 mtiles x 4 kpieces; same-XCD per mtile
#define ITERS 16                 // K-iters per block (8 feats = 96 k-slots each)
#define APAD_ROW 120             // 96 slots + 24 pad
#define SW_ROW (IN_F * 11)       // 5632 floats per output row of spline_weight
#define KC_PAD 776               // prep kcol row stride (ushorts)

typedef __bf16 bf16x8 __attribute__((ext_vector_type(8)));
typedef float f32x16 __attribute__((ext_vector_type(16)));

// frag-linear B: uint4 index (k16*16 + ntile)*64 + lane -> 8 bf16 =
//   B[k16*16 + (lane>>5)*8 + j][ntile*32 + (lane&31)],  k = f*12 + j_slot
__device__ ushort g_Wb[K16S * 16 * 64 * 8];   // 6.29 MB

__device__ __forceinline__ ushort f2bf(float f) {
    uint32_t u = __builtin_bit_cast(uint32_t, f);
    u += 0x7FFFu + ((u >> 16) & 1u);          // RNE
    return (ushort)(u >> 16);
}

// ---- weight prep: 16 ntile x 8 kgroup blocks; coalesced in AND out ---------
__global__ __launch_bounds__(256) void prep_weights(const float* __restrict__ bw,
                                                    const float* __restrict__ sw) {
    __shared__ __align__(16) ushort kcol[32 * KC_PAD];    // 48.5 KB
    const int t  = threadIdx.x;
    const int nt = blockIdx.x & 15;           // outs [nt*32, +32)
    const int kg = blockIdx.x >> 4;           // feats [kg*64, +64) -> k16 [kg*48, +48)
    const int o0 = nt * 32;
    const int f0 = kg * 64;

    {
        const int o_l = t >> 3;               // 0..31
        const int tr  = t & 7;                // 8 threads per row
        const float* swr = sw + (size_t)(o0 + o_l) * SW_ROW + (size_t)f0 * 11;
        #pragma unroll
        for (int i = 0; i < 22; ++i) {
            int p4 = tr + i * 8;              // float4 idx 0..175
            float4 v = ((const float4*)swr)[p4];
            uint pos = (uint)p4 * 4;
            #pragma unroll
            for (int c = 0; c < 4; ++c) {
                uint pc = pos + c;            // 0..703
                uint fl = pc / 11u;
                uint j  = pc - fl * 11u;
                float val = (c == 0) ? v.x : (c == 1) ? v.y : (c == 2) ? v.z : v.w;
                kcol[o_l * KC_PAD + fl * NSLOT + j] = f2bf(val);
            }
        }
        #pragma unroll
        for (int i = 0; i < 8; ++i) {
            int fl = tr + i * 8;              // 0..63
            kcol[o_l * KC_PAD + fl * NSLOT + 11] =
                f2bf(bw[(size_t)(o0 + o_l) * IN_F + f0 + fl]);
        }
    }
    __syncthreads();

    {
        const int ol = t & 31;
        const int ph = t >> 5;                // 0..7
        #pragma unroll
        for (int i = 0; i < 12; ++i) {
            int idx  = ph + i * 8;            // 0..95
            int k16l = idx >> 1;
            int half = idx & 1;
            uint4 val = *(const uint4*)&kcol[ol * KC_PAD + k16l * 16 + half * 8];
            ((uint4*)g_Wb)[((size_t)((kg * 48 + k16l) * 16 + nt)) * 64 + half * 32 + ol] = val;
        }
    }
}

// ---- basis eval + select-pack for one x value -> 3x ds_write_b64 -----------
__device__ __forceinline__ void stage_one(float xx, ushort* rowp) {
    float wpos = (xx + 1.0f) * 7.0f;
    float fi = floorf(wpos);
    int   i  = (int)fi;
    float u  = wpos - fi;
    bool inr = (xx >= -1.0f) && (xx < 1.0f);
    int   q  = i - 3;
    float um = 1.0f - u;
    float uu = u * u, u3 = uu * u;
    const float C6 = 1.0f / 6.0f;
    float s0 = (inr && q >= 0) ? C6 : 0.0f;
    float s1 = (inr && q >= -1 && q <= 9) ? C6 : 0.0f;
    float s2 = (inr && q >= -2 && q <= 8) ? C6 : 0.0f;
    float s3 = (inr && q <= 7) ? C6 : 0.0f;
    uint b0 = f2bf(um * um * um * s0);
    uint b1 = f2bf((3.0f * u3 - 6.0f * uu + 4.0f) * s1);
    uint b2 = f2bf((-3.0f * u3 + 3.0f * uu + 3.0f * u + 1.0f) * s2);
    uint b3 = f2bf(u3 * s3);
    int r  = q & 1;
    int e0 = q & ~1;
    uint P0 = r ? (b0 << 16)        : (b0 | (b1 << 16));
    uint P1 = r ? (b1 | (b2 << 16)) : (b2 | (b3 << 16));
    uint P2 = r ? b3                : 0u;
    uint p[6];
    #pragma unroll
    for (int pi = 0; pi < 6; ++pi) {
        int d = 2 * pi - e0;
        p[pi] = (d == 0) ? P0 : (d == 2) ? P1 : (d == 4) ? P2 : 0u;
    }
    p[5] = (p[5] & 0xFFFFu) | ((uint)f2bf(xx) << 16);   // slot 11 = raw x
    uint2 w0; w0.x = p[0]; w0.y = p[1];
    uint2 w1; w1.x = p[2]; w1.y = p[3];
    uint2 w2; w2.x = p[4]; w2.y = p[5];
    *(uint2*)&rowp[0] = w0;
    *(uint2*)&rowp[4] = w1;
    *(uint2*)&rowp[8] = w2;
}

// ---- fused basis + GEMM: 128 x 512 tile, K-split x4, SW-pipelined ----------
__global__ __launch_bounds__(512, 2) void kan_gemm(const float* __restrict__ x,
                                                   float* __restrict__ out) {
    __shared__ __align__(16) ushort As[2][128 * APAD_ROW];   // 2 x 30720 B

    const int t    = threadIdx.x;
    const int lane = t & 63;
    const int w    = t >> 6;          // 0..7
    const int ln31 = lane & 31;
    const int half = lane >> 5;

    const int bx = blockIdx.x;
    const int mb = bx & 63;           // M-tile; bx%8 = mb%8 -> all 4 kp same XCD
    const int kp = bx >> 6;           // K-piece 0..3
    const int row_base = mb * 128;
    const int wn = w * 64;            // wave col base (wave tile 128 x 64)

    const int sm = t >> 2;            // staging row 0..127
    const int fh = t & 3;             // 2 feats per thread: fh*2, fh*2+1

    f32x16 acc[4][2] = {};            // 4 M-subtiles x 2 N-subtiles

    const float* xrow = x + (size_t)(row_base + sm) * IN_F + kp * 128 + fh * 2;
    ushort* const myrow0 = &As[0][sm * APAD_ROW + fh * 2 * NSLOT];
    ushort* const myrow1 = &As[1][sm * APAD_ROW + fh * 2 * NSLOT];

    // ---- prologue: stage tile 0, prefetch x(1)
    float2 xv = *(const float2*)xrow;                 // x(0)
    stage_one(xv.x, myrow0);
    stage_one(xv.y, myrow0 + NSLOT);
    float2 xv_n = *(const float2*)(xrow + 8);         // x(1)
    __syncthreads();                                  // publish As[0]

    #pragma unroll 2
    for (int ii = 0; ii < ITERS; ++ii) {
        const int cur = ii & 1;
        // -- B frags for THIS iteration (latency hidden behind staging phase)
        uint4 breg[6][2];
        #pragma unroll
        for (int ks = 0; ks < 6; ++ks) {
            int k16g = kp * 96 + ii * 6 + ks;
            #pragma unroll
            for (int nt = 0; nt < 2; ++nt) {
                breg[ks][nt] = ((const uint4*)g_Wb)[((size_t)k16g * 16 + w * 2 + nt) * 64 + lane];
            }
        }
        // -- prefetch x(ii+2) (clamped; garbage reuse at tail is never consumed)
        int itf = (ii + 2 < ITERS) ? (ii + 2) : (ITERS - 1);
        float2 xv_f = *(const float2*)(xrow + itf * 8);

        // -- stage basis(ii+1) into the OTHER buffer (no barrier needed: cur/nxt disjoint)
        ushort* nrow = cur ? myrow0 : myrow1;
        stage_one(xv_n.x, nrow);
        stage_one(xv_n.y, nrow + NSLOT);

        // -- MFMA from As[cur]
        const ushort* Ac = As[cur];
        #pragma unroll
        for (int ks = 0; ks < 6; ++ks) {
            uint4 a[4];
            #pragma unroll
            for (int mt = 0; mt < 4; ++mt)
                a[mt] = *(const uint4*)&Ac[(mt * 32 + ln31) * APAD_ROW + ks * 16 + half * 8];
            #pragma unroll
            for (int mt = 0; mt < 4; ++mt) {
                bf16x8 af = __builtin_bit_cast(bf16x8, a[mt]);
                #pragma unroll
                for (int nt = 0; nt < 2; ++nt) {
                    bf16x8 bf = __builtin_bit_cast(bf16x8, breg[ks][nt]);
                    acc[mt][nt] = __builtin_amdgcn_mfma_f32_32x32x16_bf16(af, bf, acc[mt][nt], 0, 0, 0);
                }
            }
        }

        xv_n = xv_f;
        __syncthreads();   // publish As[nxt]; guards buffer reuse next iteration
    }

    // -- epilogue: C layout col=lane&31, row=(reg&3)+8*(reg>>2)+4*(lane>>5)
    #pragma unroll
    for (int mt = 0; mt < 4; ++mt) {
        #pragma unroll
        for (int nt = 0; nt < 2; ++nt) {
            int rb = row_base + mt * 32 + 4 * half;
            int cc = wn + nt * 32 + ln31;
            #pragma unroll
            for (int reg = 0; reg < 16; ++reg) {
                int rr = rb + (reg & 3) + 8 * (reg >> 2);
                unsafeAtomicAdd(&out[(size_t)rr * OUT_F + cc], acc[mt][nt][reg]);
            }
        }
    }
}

extern "C" void kernel_launch(void* const* d_in, const int* in_sizes, int n_in,
                              void* d_out, int out_size, void* d_ws, size_t ws_size,
                              hipStream_t stream) {
    const float* x  = (const float*)d_in[0];
    const float* bw = (const float*)d_in[1];
    const float* sw = (const float*)d_in[2];
    float* out = (float*)d_out;
    hipMemsetAsync(out, 0, (size_t)out_size * sizeof(float), stream);
    hipLaunchKernelGGL(prep_weights, dim3(128), dim3(256), 0, stream, bw, sw);
    hipLaunchKernelGGL(kan_gemm, dim3(64 * KSPLIT), dim3(512), 0, stream, x, out);
}